// Round 1
// baseline (17327.766 us; speedup 1.0000x reference)
//
#include <hip/hip_runtime.h>
#include <stddef.h>

// Problem dims (fixed by the reference)
#define BB 32
#define TT 2048
#define NI 128
#define NH 512
#define NO 128

// d_out layout (floats): z[BB*NO] | X[BB*TT*NH] | As[BB*TT*NH] | Phis[BB*TT*NH]
#define Z_OFS   0
#define X_OFS   (BB * NO)
#define AS_OFS  (X_OFS + (size_t)BB * TT * NH)
#define PHI_OFS (AS_OFS + (size_t)BB * TT * NH)

// ---------------------------------------------------------------------------
// Kernel 1: WrT[k][h] = Wr[h][k]  (coalesced tile transpose into d_ws)
// ---------------------------------------------------------------------------
__global__ void __launch_bounds__(256) transpose_wr(const float* __restrict__ Wr,
                                                    float* __restrict__ WrT) {
    __shared__ float tile[32][33];
    const int k0 = blockIdx.x * 32;
    const int h0 = blockIdx.y * 32;
    const int tx = threadIdx.x;   // 0..31
    const int ty = threadIdx.y;   // 0..7
    for (int i = ty; i < 32; i += 8)
        tile[i][tx] = Wr[(size_t)(h0 + i) * NH + k0 + tx];
    __syncthreads();
    for (int i = ty; i < 32; i += 8)
        WrT[(size_t)(k0 + i) * NH + h0 + tx] = tile[tx][i];
}

// ---------------------------------------------------------------------------
// Kernel 2: ui[bt][h] = sum_k u[bt][k] * Wi[h][k]   (written into As region)
// Tiled f32 GEMM: M=BB*TT, N=NH, K=NI. 64x64 tile, 256 threads, 4x4 microtile.
// ---------------------------------------------------------------------------
__global__ void __launch_bounds__(256) ui_gemm(const float* __restrict__ u,
                                               const float* __restrict__ Wi,
                                               float* __restrict__ ui_out) {
    __shared__ float Au[64][NI + 1];  // +1 pad: LDS bank spread
    __shared__ float Bw[64][NI + 1];
    const int tid = threadIdx.x;
    const int bt0 = blockIdx.x * 64;
    const int h0  = blockIdx.y * 64;

    // Load both 64x128 tiles; 2048 float4s per tile over 256 threads
    for (int idx = tid; idx < 64 * (NI / 4); idx += 256) {
        const int r = idx >> 5;          // 0..63
        const int c = (idx & 31) << 2;   // 0..124
        float4 va = *reinterpret_cast<const float4*>(&u[(size_t)(bt0 + r) * NI + c]);
        Au[r][c + 0] = va.x; Au[r][c + 1] = va.y; Au[r][c + 2] = va.z; Au[r][c + 3] = va.w;
        float4 vb = *reinterpret_cast<const float4*>(&Wi[(size_t)(h0 + r) * NI + c]);
        Bw[r][c + 0] = vb.x; Bw[r][c + 1] = vb.y; Bw[r][c + 2] = vb.z; Bw[r][c + 3] = vb.w;
    }
    __syncthreads();

    const int tx = tid & 15;   // h micro
    const int ty = tid >> 4;   // bt micro
    float acc[4][4] = {};
    for (int k = 0; k < NI; ++k) {
        float a_[4], b_[4];
#pragma unroll
        for (int i = 0; i < 4; ++i) a_[i] = Au[ty * 4 + i][k];
#pragma unroll
        for (int j = 0; j < 4; ++j) b_[j] = Bw[tx * 4 + j][k];
#pragma unroll
        for (int i = 0; i < 4; ++i)
#pragma unroll
            for (int j = 0; j < 4; ++j) acc[i][j] += a_[i] * b_[j];
    }
#pragma unroll
    for (int i = 0; i < 4; ++i)
#pragma unroll
        for (int j = 0; j < 4; ++j)
            ui_out[(size_t)(bt0 + ty * 4 + i) * NH + (h0 + tx * 4 + j)] = acc[i][j];
}

// ---------------------------------------------------------------------------
// Kernel 3: the sequential scan. One workgroup per batch (recurrences are
// independent across b). 512 threads: h-quad q = tid&127, k-group g = tid>>7.
// x state lives in LDS; WrT streamed from L2 (1 MB/step, fits per-XCD L2).
// ---------------------------------------------------------------------------
__global__ void __launch_bounds__(512) rnn_scan(const float* __restrict__ WrT,
                                                float* __restrict__ out) {
    const int b   = blockIdx.x;
    const int tid = threadIdx.x;
    const int q   = tid & 127;   // h-quad: h = 4q..4q+3
    const int g   = tid >> 7;    // k-group: k in [128g, 128g+128)

    __shared__ float x[NH];
    __shared__ float part[4][NH];

    for (int h = tid; h < NH; h += 512) x[h] = 0.0f;
    __syncthreads();

    float* __restrict__ Xp   = out + X_OFS   + (size_t)b * TT * NH;
    float* __restrict__ Asp  = out + AS_OFS  + (size_t)b * TT * NH;
    float* __restrict__ Php  = out + PHI_OFS + (size_t)b * TT * NH;

    const float* wbase = WrT + (size_t)g * 128 * NH + q * 4;

    for (int t = 0; t < TT; ++t) {
        float4 acc = make_float4(0.f, 0.f, 0.f, 0.f);
        const float* wp = wbase;
#pragma unroll 4
        for (int kk4 = 0; kk4 < 32; ++kk4) {
            float4 xv = *reinterpret_cast<const float4*>(&x[g * 128 + kk4 * 4]);
            float4 w0 = *reinterpret_cast<const float4*>(wp);
            float4 w1 = *reinterpret_cast<const float4*>(wp + NH);
            float4 w2 = *reinterpret_cast<const float4*>(wp + 2 * NH);
            float4 w3 = *reinterpret_cast<const float4*>(wp + 3 * NH);
            acc.x += xv.x * w0.x + xv.y * w1.x + xv.z * w2.x + xv.w * w3.x;
            acc.y += xv.x * w0.y + xv.y * w1.y + xv.z * w2.y + xv.w * w3.y;
            acc.z += xv.x * w0.z + xv.y * w1.z + xv.z * w2.z + xv.w * w3.z;
            acc.w += xv.x * w0.w + xv.y * w1.w + xv.z * w2.w + xv.w * w3.w;
            wp += 4 * NH;
        }
        *reinterpret_cast<float4*>(&part[g][q * 4]) = acc;
        __syncthreads();   // all k-loop reads of x done; partials visible

        const int h = tid;
        float a = part[0][h] + part[1][h] + part[2][h] + part[3][h];
        a += Asp[(size_t)t * NH + h];              // ui (precomputed into As region)
        const float phi = tanhf(a);
        x[h] = phi;                                 // safe: everyone past k-loop
        Asp[(size_t)t * NH + h] = a;
        Xp [(size_t)t * NH + h] = phi;
        Php[(size_t)t * NH + h] = phi;
        __syncthreads();   // x writes visible; part reads done before overwrite
    }
}

// ---------------------------------------------------------------------------
// Kernel 4: z[b][o] = sum_h X[b][T-1][h] * Wo[o][h]
// ---------------------------------------------------------------------------
__global__ void __launch_bounds__(128) z_gemv(const float* __restrict__ Wo,
                                              float* __restrict__ out) {
    const int b = blockIdx.x;
    const int o = threadIdx.x;
    __shared__ float xl[NH];
    const float* Xlast = out + X_OFS + (size_t)b * TT * NH + (size_t)(TT - 1) * NH;
    for (int h = threadIdx.x; h < NH; h += 128) xl[h] = Xlast[h];
    __syncthreads();
    float acc = 0.f;
#pragma unroll 4
    for (int h4 = 0; h4 < NH / 4; ++h4) {
        float4 w = *reinterpret_cast<const float4*>(&Wo[(size_t)o * NH + h4 * 4]);
        acc += xl[h4 * 4 + 0] * w.x + xl[h4 * 4 + 1] * w.y +
               xl[h4 * 4 + 2] * w.z + xl[h4 * 4 + 3] * w.w;
    }
    out[Z_OFS + (size_t)b * NO + o] = acc;
}

// ---------------------------------------------------------------------------
extern "C" void kernel_launch(void* const* d_in, const int* in_sizes, int n_in,
                              void* d_out, int out_size, void* d_ws, size_t ws_size,
                              hipStream_t stream) {
    const float* u  = (const float*)d_in[0];
    const float* Wr = (const float*)d_in[1];
    const float* Wi = (const float*)d_in[2];
    const float* Wo = (const float*)d_in[3];
    float* out = (float*)d_out;
    float* WrT = (float*)d_ws;   // needs NH*NH*4 = 1 MB of scratch

    transpose_wr<<<dim3(NH / 32, NH / 32), dim3(32, 8), 0, stream>>>(Wr, WrT);

    // ui -> As region of d_out (scan reads it there, then overwrites with a)
    ui_gemm<<<dim3((BB * TT) / 64, NH / 64), 256, 0, stream>>>(u, Wi, out + AS_OFS);

    rnn_scan<<<BB, 512, 0, stream>>>(WrT, out);

    z_gemv<<<BB, 128, 0, stream>>>(Wo, out);
}

// Round 2
// 7425.566 us; speedup vs baseline: 2.3335x; 2.3335x over previous
//
#include <hip/hip_runtime.h>
#include <stddef.h>
#include <stdint.h>

// Problem dims (fixed by the reference)
#define BB 32
#define TT 2048
#define NI 128
#define NH 512
#define NO 128

// d_out layout (floats): z[BB*NO] | X[BB*TT*NH] | As[BB*TT*NH] | Phis[BB*TT*NH]
#define Z_OFS   0
#define X_OFS   (BB * NO)
#define AS_OFS  (X_OFS + (size_t)BB * TT * NH)
#define PHI_OFS (AS_OFS + (size_t)BB * TT * NH)

// Scan decomposition: 4 WGs per batch, each owns a 128-row h-slice of Wr
// entirely in VGPRs (64 f32/thread @ 1024 threads). Per-step state exchange
// via global xbuf + per-step arrival counters (agent-scope atomics).
#define WGPB 4
#define HSL  (NH / WGPB)   // 128 h per WG
#define NG   8             // k-groups per WG
#define KG   (NH / NG)     // 64 k per group
#define NTHR 1024

// d_ws layout (bytes):
//   xbuf: [2][BB][NH] f32   = 131072 B
//   cnt : [BB][TT]   u32    = 262144 B
#define XBUF_BYTES (2 * BB * NH * 4)
#define CNT_BYTES  (BB * TT * 4)

// ---------------------------------------------------------------------------
// Kernel 1: ui[bt][h] = sum_k u[bt][k] * Wi[h][k]   (written into As region)
// ---------------------------------------------------------------------------
__global__ void __launch_bounds__(256) ui_gemm(const float* __restrict__ u,
                                               const float* __restrict__ Wi,
                                               float* __restrict__ ui_out) {
    __shared__ float Au[64][NI + 1];
    __shared__ float Bw[64][NI + 1];
    const int tid = threadIdx.x;
    const int bt0 = blockIdx.x * 64;
    const int h0  = blockIdx.y * 64;

    for (int idx = tid; idx < 64 * (NI / 4); idx += 256) {
        const int r = idx >> 5;
        const int c = (idx & 31) << 2;
        float4 va = *reinterpret_cast<const float4*>(&u[(size_t)(bt0 + r) * NI + c]);
        Au[r][c + 0] = va.x; Au[r][c + 1] = va.y; Au[r][c + 2] = va.z; Au[r][c + 3] = va.w;
        float4 vb = *reinterpret_cast<const float4*>(&Wi[(size_t)(h0 + r) * NI + c]);
        Bw[r][c + 0] = vb.x; Bw[r][c + 1] = vb.y; Bw[r][c + 2] = vb.z; Bw[r][c + 3] = vb.w;
    }
    __syncthreads();

    const int tx = tid & 15;
    const int ty = tid >> 4;
    float acc[4][4] = {};
    for (int k = 0; k < NI; ++k) {
        float a_[4], b_[4];
#pragma unroll
        for (int i = 0; i < 4; ++i) a_[i] = Au[ty * 4 + i][k];
#pragma unroll
        for (int j = 0; j < 4; ++j) b_[j] = Bw[tx * 4 + j][k];
#pragma unroll
        for (int i = 0; i < 4; ++i)
#pragma unroll
            for (int j = 0; j < 4; ++j) acc[i][j] += a_[i] * b_[j];
    }
#pragma unroll
    for (int i = 0; i < 4; ++i)
#pragma unroll
        for (int j = 0; j < 4; ++j)
            ui_out[(size_t)(bt0 + ty * 4 + i) * NH + (h0 + tx * 4 + j)] = acc[i][j];
}

// ---------------------------------------------------------------------------
// Kernel 2: multi-WG scan. WG wg handles batch b = wg % BB, h-slice
// j = wg / BB (rows [j*128, j*128+128)). Weights live in VGPRs for the
// entire 2048-step loop; per-step cross-WG exchange of the 512-float state.
// ---------------------------------------------------------------------------
__global__ void __launch_bounds__(NTHR) rnn_scan_mw(const float* __restrict__ Wr,
                                                    float* __restrict__ out,
                                                    float* __restrict__ xbuf,
                                                    unsigned int* __restrict__ cnt) {
    const int wg  = blockIdx.x;       // 0..127
    const int b   = wg % BB;          // batch (same-batch WGs land on same XCD
    const int j   = wg / BB;          //  under round-robin blockIdx%8 mapping)
    const int h0  = j * HSL;
    const int tid = threadIdx.x;
    const int hh  = tid & (HSL - 1);  // h within slice
    const int g   = tid >> 7;         // k-group 0..7

    __shared__ float x_lds[NH];
    __shared__ float part[NG][HSL];

    // --- Load this thread's weight stripe: Wr[h0+hh][g*64 .. g*64+63] -> 64 VGPRs
    float4 w[16];
    {
        const float* wrow = Wr + (size_t)(h0 + hh) * NH + g * KG;
#pragma unroll
        for (int i = 0; i < 16; ++i)
            w[i] = reinterpret_cast<const float4*>(wrow)[i];
    }

    float* __restrict__ Xp  = out + X_OFS   + (size_t)b * TT * NH;
    float* __restrict__ Asp = out + AS_OFS  + (size_t)b * TT * NH;
    float* __restrict__ Php = out + PHI_OFS + (size_t)b * TT * NH;
    unsigned int* mycnt = cnt + (size_t)b * TT;

    // x0 = 0
    if (tid < NH) x_lds[tid] = 0.0f;
    // (no barrier needed: same thread re-touches x_lds[tid] below, and the
    //  staging barrier precedes all cross-thread reads)

    for (int t = 0; t < TT; ++t) {
        const size_t o = (size_t)t * NH + h0 + hh;  // valid for tid < HSL
        float uival = 0.0f;
        if (tid < HSL) uival = Asp[o];              // prefetch ui (hides HBM lat)

        // stage x_t: remote slices only (own slice self-written last step)
        if (tid < NH && (tid >> 7) != j) {
            const float* xsrc = xbuf + ((size_t)(t & 1) * BB + b) * NH;
            x_lds[tid] = xsrc[tid];
        }
        __syncthreads();

        // dot: a_partial[h0+hh] over k in [g*64, g*64+64)
        float acc = 0.0f;
#pragma unroll
        for (int i = 0; i < 16; ++i) {
            float4 xv = *reinterpret_cast<const float4*>(&x_lds[g * KG + 4 * i]);
            acc += w[i].x * xv.x + w[i].y * xv.y + w[i].z * xv.z + w[i].w * xv.w;
        }
        part[g][hh] = acc;
        __syncthreads();

        if (tid < HSL) {
            float a = uival;
#pragma unroll
            for (int gg = 0; gg < NG; ++gg) a += part[gg][tid];
            const float phi = tanhf(a);
            Asp[o] = a;
            Xp [o] = phi;
            Php[o] = phi;
            x_lds[h0 + tid] = phi;   // own slice for next step (local)
            xbuf[((size_t)((t + 1) & 1) * BB + b) * NH + h0 + tid] = phi;
        }
        __syncthreads();   // drain stores (syncthreads waits vmcnt) before arrive

        if (tid == 0) {
            __hip_atomic_fetch_add(&mycnt[t], 1u, __ATOMIC_RELEASE,
                                   __HIP_MEMORY_SCOPE_AGENT);
            while (__hip_atomic_load(&mycnt[t], __ATOMIC_RELAXED,
                                     __HIP_MEMORY_SCOPE_AGENT) < WGPB) { }
            __builtin_amdgcn_fence(__ATOMIC_ACQUIRE, "agent");
        }
        __syncthreads();
    }
}

// ---------------------------------------------------------------------------
// Kernel 3: z[b][o] = sum_h X[b][T-1][h] * Wo[o][h]
// ---------------------------------------------------------------------------
__global__ void __launch_bounds__(128) z_gemv(const float* __restrict__ Wo,
                                              float* __restrict__ out) {
    const int b = blockIdx.x;
    const int o = threadIdx.x;
    __shared__ float xl[NH];
    const float* Xlast = out + X_OFS + (size_t)b * TT * NH + (size_t)(TT - 1) * NH;
    for (int h = threadIdx.x; h < NH; h += 128) xl[h] = Xlast[h];
    __syncthreads();
    float acc = 0.f;
#pragma unroll 4
    for (int h4 = 0; h4 < NH / 4; ++h4) {
        float4 w = *reinterpret_cast<const float4*>(&Wo[(size_t)o * NH + h4 * 4]);
        acc += xl[h4 * 4 + 0] * w.x + xl[h4 * 4 + 1] * w.y +
               xl[h4 * 4 + 2] * w.z + xl[h4 * 4 + 3] * w.w;
    }
    out[Z_OFS + (size_t)b * NO + o] = acc;
}

// ---------------------------------------------------------------------------
extern "C" void kernel_launch(void* const* d_in, const int* in_sizes, int n_in,
                              void* d_out, int out_size, void* d_ws, size_t ws_size,
                              hipStream_t stream) {
    const float* u  = (const float*)d_in[0];
    const float* Wr = (const float*)d_in[1];
    const float* Wi = (const float*)d_in[2];
    const float* Wo = (const float*)d_in[3];
    float* out = (float*)d_out;

    float*        xbuf = (float*)d_ws;
    unsigned int* cnt  = (unsigned int*)((char*)d_ws + XBUF_BYTES);

    // zero xbuf (x0 = 0) and the per-step arrival counters (every replay)
    hipMemsetAsync(d_ws, 0, XBUF_BYTES + CNT_BYTES, stream);

    // ui -> As region of d_out (scan reads it there, then overwrites with a)
    ui_gemm<<<dim3((BB * TT) / 64, NH / 64), 256, 0, stream>>>(u, Wi, out + AS_OFS);

    rnn_scan_mw<<<BB * WGPB, NTHR, 0, stream>>>(Wr, out, xbuf, cnt);

    z_gemv<<<BB, 128, 0, stream>>>(Wo, out);
}